// Round 18
// baseline (147.717 us; speedup 1.0000x reference)
//
#include <hip/hip_runtime.h>
#include <hip/hip_bf16.h>

typedef __attribute__((ext_vector_type(4))) float f32x4;
typedef __attribute__((ext_vector_type(16))) float f32x16;
typedef __attribute__((ext_vector_type(8))) short short8;

#define LOG2E 1.4426950408889634f

__device__ __forceinline__ unsigned short f2bf(float f) {
  union { float f; unsigned u; } v; v.f = f;
  unsigned r = v.u + 0x7FFFu + ((v.u >> 16) & 1u);
  return (unsigned short)(r >> 16);
}

__device__ __forceinline__ void gload_lds16(const unsigned short* g, unsigned short* l) {
  __builtin_amdgcn_global_load_lds((const __attribute__((address_space(1))) void*)g,
                                   (__attribute__((address_space(3))) void*)l, 16, 0, 0);
}

// -------- weights f32 -> bf16 + mask nonzero flag (activations fused in GEMM) --------
__global__ void cvt_kernel(const float* __restrict__ wq, const float* __restrict__ wk,
                           const float* __restrict__ wv, const float* __restrict__ wo,
                           const float* __restrict__ mask,
                           unsigned short* __restrict__ wqb, unsigned short* __restrict__ wkb,
                           unsigned short* __restrict__ wvb, unsigned short* __restrict__ wob,
                           int* __restrict__ flag) {
  const size_t W1 = 262144;  // 1M f32 / 4 per unit
  size_t u = (size_t)blockIdx.x * 256 + threadIdx.x;
  const float* src; unsigned short* dst; size_t loc;
  if (u < W1)          { src = wq; dst = wqb; loc = u; }
  else if (u < 2 * W1) { src = wk; dst = wkb; loc = u - W1; }
  else if (u < 3 * W1) { src = wv; dst = wvb; loc = u - 2 * W1; }
  else if (u < 4 * W1) { src = wo; dst = wob; loc = u - 3 * W1; }
  else {
    loc = u - 4 * W1;  // mask: 4M f32 = 1M units
    float4 f = ((const float4*)mask)[loc];
    if (f.x != 0.f || f.y != 0.f || f.z != 0.f || f.w != 0.f) atomicOr(flag, 1);
    return;
  }
  float4 f = ((const float4*)src)[loc];
  ushort4 o;
  o.x = f2bf(f.x); o.y = f2bf(f.y); o.z = f2bf(f.z); o.w = f2bf(f.w);
  ((ushort4*)dst)[loc] = o;
}

// ---------------- QKV projections: C = A_f32 * B_bf16^T, fused conversion ----
// r11 structure (session-best total): BM=BN=128, BK=32, 512 threads (8 waves,
// 4m x 2n). A staged via registers (f32 load -> f2bf -> ds_write_b128 at the
// pre-swizzled slot) with the T14 issue-early/write-late split: loads issue
// right after the barrier, ds_write lands after the MFMA block, so HBM latency
// hides under compute. B staged via global_load_lds (bf16 weights).
// XOR-swizzled LDS, dbuf, 1 barrier per K-step. + r17 bijective XCD swizzle.
__global__ __launch_bounds__(512)
void gemm_qkv_kernel(const float* __restrict__ qin, const float* __restrict__ kin,
                     const float* __restrict__ vin,
                     const unsigned short* __restrict__ wq, const unsigned short* __restrict__ wk,
                     const unsigned short* __restrict__ wv,
                     unsigned short* __restrict__ Qbf, unsigned short* __restrict__ Kbf,
                     unsigned short* __restrict__ Vt,
                     float* __restrict__ kcache, float* __restrict__ vcache) {
  __shared__ __align__(16) unsigned short As[2 * 4096];
  __shared__ __align__(16) unsigned short Bs[2 * 4096];
  const int z = blockIdx.z;
  const float* Af = (z == 0) ? qin : (z == 1) ? kin : vin;
  const unsigned short* B = (z == 0) ? wq : (z == 1) ? wk : wv;
  // XCD swizzle within each z-slice (256 blocks, bijective since 256%8==0)
  int orig = blockIdx.x + 32 * blockIdx.y;
  int logical = (orig & 7) * 32 + (orig >> 3);
  const int m0 = (logical & 31) * 128, n0 = (logical >> 5) * 128;
  const int t = threadIdx.x, lane = t & 63, w = t >> 6;
  const int wr = (w >> 1) << 5, wc = (w & 1) << 6;
  const int lo = lane & 15, hi = lane >> 4;
  const int swz = (hi ^ ((lo >> 1) & 3)) * 8;

  f32x4 acc[2][4];
#pragma unroll
  for (int i = 0; i < 2; ++i)
#pragma unroll
    for (int j = 0; j < 4; ++j) acc[i][j] = f32x4{0.f, 0.f, 0.f, 0.f};

  const int c0 = t, row0 = c0 >> 2;
  const int gsw0 = ((c0 & 3) ^ ((row0 >> 1) & 3)) << 3;
  const float* Arow = Af + (size_t)(m0 + row0) * 1024 + gsw0;
  const unsigned short* Br0 = B + (size_t)(n0 + row0) * 1024 + gsw0;

  float4 a0, a1;
  auto loadA = [&](int kt) {
    a0 = *(const float4*)(Arow + kt);
    a1 = *(const float4*)(Arow + kt + 4);
  };
  auto writeA = [&](int buf) {
    short8 w8;
    w8[0] = (short)f2bf(a0.x); w8[1] = (short)f2bf(a0.y);
    w8[2] = (short)f2bf(a0.z); w8[3] = (short)f2bf(a0.w);
    w8[4] = (short)f2bf(a1.x); w8[5] = (short)f2bf(a1.y);
    w8[6] = (short)f2bf(a1.z); w8[7] = (short)f2bf(a1.w);
    *(short8*)&As[buf * 4096 + c0 * 8] = w8;
  };
  auto stageB = [&](int kt, int buf) { gload_lds16(Br0 + kt, &Bs[buf * 4096 + c0 * 8]); };

  loadA(0); stageB(0, 0); writeA(0);
  for (int it = 0; it < 32; ++it) {
    __syncthreads();  // buf it&1 ready (A ds_writes + B gload drained); (it+1)&1 free
    if (it + 1 < 32) { loadA((it + 1) * 32); stageB((it + 1) * 32, (it + 1) & 1); }
    const unsigned short* Ac = &As[(it & 1) * 4096];
    const unsigned short* Bc = &Bs[(it & 1) * 4096];
    short8 af[2], bfr[4];
#pragma unroll
    for (int i = 0; i < 2; ++i) af[i]  = *(const short8*)&Ac[(wr + i*16 + lo) * 32 + swz];
#pragma unroll
    for (int j = 0; j < 4; ++j) bfr[j] = *(const short8*)&Bc[(wc + j*16 + lo) * 32 + swz];
#pragma unroll
    for (int i = 0; i < 2; ++i)
#pragma unroll
      for (int j = 0; j < 4; ++j)
        acc[i][j] = __builtin_amdgcn_mfma_f32_16x16x32_bf16(af[i], bfr[j], acc[i][j], 0, 0, 0);
    if (it + 1 < 32) writeA((it + 1) & 1);  // late write: loads landed under the MFMAs
  }

#pragma unroll
  for (int i = 0; i < 2; ++i)
#pragma unroll
    for (int j = 0; j < 4; ++j) {
      int n = n0 + wc + j * 16 + lo;
      int head = n >> 6, dk = n & 63;
      int mbase = m0 + wr + i * 16 + hi * 4;
      int b = mbase >> 11, sbase = mbase & 2047;
      size_t bh = (size_t)b * 16 + head;
      if (z == 0) {
#pragma unroll
        for (int r = 0; r < 4; ++r)
          Qbf[(bh * 2048 + sbase + r) * 64 + dk] = f2bf(acc[i][j][r] * LOG2E);
      } else if (z == 1) {
#pragma unroll
        for (int r = 0; r < 4; ++r)
          Kbf[(bh * 2048 + sbase + r) * 64 + dk] = f2bf(acc[i][j][r]);
        float4 kv4;
        kv4.x = acc[i][j][0]; kv4.y = acc[i][j][1];
        kv4.z = acc[i][j][2]; kv4.w = acc[i][j][3];
        *(float4*)&kcache[(bh * 64 + dk) * 2048 + sbase] = kv4;
      } else {
#pragma unroll
        for (int r = 0; r < 4; ++r)
          vcache[(bh * 2048 + sbase + r) * 64 + dk] = acc[i][j][r];
        ushort4 vt4;
        vt4.x = f2bf(acc[i][j][0]); vt4.y = f2bf(acc[i][j][1]);
        vt4.z = f2bf(acc[i][j][2]); vt4.w = f2bf(acc[i][j][3]);
        *(ushort4*)&Vt[(bh * 64 + dk) * 2048 + sbase] = vt4;
      }
    }
}

// ---------------- GEMM core for gemm_o (bf16 x bf16), BN templated ----------
template <int BN>
__device__ __forceinline__ void gemm_bt_core(const unsigned short* __restrict__ A,
                                             const unsigned short* __restrict__ B,
                                             unsigned short* As, unsigned short* Bs,
                                             int m0, int n0, f32x4 acc[2][BN / 32]) {
  constexpr int NJ = BN / 32;
  constexpr int BSLOTS = BN * 4;
  const int t = threadIdx.x, lane = t & 63, w = t >> 6;
  const int wr = (w >> 1) << 5;
  const int wc = (w & 1) * (BN / 2);
  const int lo = lane & 15, hi = lane >> 4;
  const int swz = (hi ^ ((lo >> 1) & 3)) * 8;
#pragma unroll
  for (int i = 0; i < 2; ++i)
#pragma unroll
    for (int j = 0; j < NJ; ++j) acc[i][j] = f32x4{0.f, 0.f, 0.f, 0.f};

  const int c0 = t, row0 = c0 >> 2;
  const int gsw0 = ((c0 & 3) ^ ((row0 >> 1) & 3)) << 3;
  const unsigned short* Ar0 = A + (size_t)(m0 + row0) * 1024 + gsw0;
  const unsigned short* Br0 = (c0 < BSLOTS)
      ? B + (size_t)(n0 + row0) * 1024 + gsw0 : nullptr;

  auto stage = [&](int kt, int buf) {
    gload_lds16(Ar0 + kt, &As[buf * 4096 + c0 * 8]);
    if (BN == 128 || c0 < BSLOTS)
      gload_lds16(Br0 + kt, &Bs[buf * (BSLOTS * 8) + c0 * 8]);
  };

  stage(0, 0);
  for (int it = 0; it < 32; ++it) {
    __syncthreads();
    if (it + 1 < 32) stage((it + 1) * 32, (it + 1) & 1);
    const unsigned short* Ac = &As[(it & 1) * 4096];
    const unsigned short* Bc = &Bs[(it & 1) * (BSLOTS * 8)];
    short8 af[2], bfr[NJ];
#pragma unroll
    for (int i = 0; i < 2; ++i) af[i]  = *(const short8*)&Ac[(wr + i*16 + lo) * 32 + swz];
#pragma unroll
    for (int j = 0; j < NJ; ++j) bfr[j] = *(const short8*)&Bc[(wc + j*16 + lo) * 32 + swz];
#pragma unroll
    for (int i = 0; i < 2; ++i)
#pragma unroll
      for (int j = 0; j < NJ; ++j)
        acc[i][j] = __builtin_amdgcn_mfma_f32_16x16x32_bf16(af[i], bfr[j], acc[i][j], 0, 0, 0);
  }
}

// ---------------- output projection: BN=64 -> 512 blocks = 2 blocks/CU ------
__global__ __launch_bounds__(512)
void gemm_o_kernel(const unsigned short* __restrict__ A, const unsigned short* __restrict__ B,
                   float* __restrict__ C) {
  __shared__ __align__(16) unsigned short As[2 * 4096];
  __shared__ __align__(16) unsigned short Bs[2 * 2048];
  const int m0 = blockIdx.x * 128, n0 = blockIdx.y * 64;
  f32x4 acc[2][2];
  gemm_bt_core<64>(A, B, As, Bs, m0, n0, acc);
  const int t = threadIdx.x, lane = t & 63, w = t >> 6;
  const int wr = (w >> 1) << 5, wc = (w & 1) << 5;
  const int lo = lane & 15, hi = lane >> 4;
#pragma unroll
  for (int i = 0; i < 2; ++i)
#pragma unroll
    for (int j = 0; j < 2; ++j)
#pragma unroll
      for (int r = 0; r < 4; ++r)
        C[(size_t)(m0 + wr + i * 16 + hi * 4 + r) * 1024 + n0 + wc + j * 16 + lo] = acc[i][j][r];
}

// ---------------- flash attention, swapped-operand 32x32 MFMA (r15 best) ----
// Single-pass. 4 KV buffer pairs (64KB LDS), ONE barrier per TWO tiles.
// Independent tile streams (oA/oB, rsA/rsB; exact since no rescaling).
// Scale-invariant softmax in log2 domain (Q pre-scaled by log2e): P = exp2(s),
// no max subtraction. No setprio (r16 A/B: null-to-negative here).
__global__ __launch_bounds__(256, 2)
void attn_kernel(const unsigned short* __restrict__ Qbf,
                 const unsigned short* __restrict__ Kbf,
                 const unsigned short* __restrict__ Vtb,
                 const float* __restrict__ mask, const int* __restrict__ flag,
                 unsigned short* __restrict__ Obf) {
  __shared__ __align__(16) unsigned short Ks[4 * 4096];  // [buf][d8][slot64][8]
  __shared__ __align__(16) unsigned short Vs[4 * 4096];  // [buf][s8][dk64][8]
  const int t = threadIdx.x, lane = t & 63, w = t >> 6;
  const int q31 = lane & 31, hh = lane >> 5;

  int orig = blockIdx.x + 16 * blockIdx.y;
  int logical = (orig & 7) * 64 + (orig >> 3);
  const int bh = logical >> 4;
  const int b = bh >> 4, head = bh & 15;
  const int q = (logical & 15) * 128 + w * 32 + q31;
  const int mf = *flag;

  short8 qf[4];
  const unsigned short* Qrow = Qbf + ((size_t)bh * 2048 + q) * 64 + hh * 8;
#pragma unroll
  for (int kk = 0; kk < 4; ++kk) qf[kk] = *(const short8*)(Qrow + kk * 16);

  f32x16 oA[2], oB[2], zero16;
#pragma unroll
  for (int d = 0; d < 2; ++d)
#pragma unroll
    for (int r = 0; r < 16; ++r) { oA[d][r] = 0.f; oB[d][r] = 0.f; }
#pragma unroll
  for (int r = 0; r < 16; ++r) zero16[r] = 0.f;
  float rsA[4] = {0.f, 0.f, 0.f, 0.f};
  float rsB[4] = {0.f, 0.f, 0.f, 0.f};

  const unsigned short* Kbase = Kbf + (size_t)bh * 2048 * 64;
  const unsigned short* Vbase = Vtb + (size_t)bh * 64 * 2048;

  auto stage = [&](int st, int buf) {
#pragma unroll
    for (int cc = 0; cc < 2; ++cc) {
      int c = t + cc * 256;
      int hi6 = c >> 6, lo6 = c & 63;
      int pr = (lo6 & ~12) | ((lo6 & 4) << 1) | ((lo6 >> 1) & 4);  // bit2<->bit3
      gload_lds16(Kbase + (size_t)(st * 64 + pr) * 64 + hi6 * 8, &Ks[buf * 4096 + c * 8]);
      gload_lds16(Vbase + (size_t)lo6 * 2048 + st * 64 + hi6 * 8, &Vs[buf * 4096 + c * 8]);
    }
  };

  auto qk_tile = [&](const unsigned short* Kc, f32x16 (&sf)[2]) {
#pragma unroll
    for (int kk = 0; kk < 4; ++kk)
#pragma unroll
      for (int i = 0; i < 2; ++i) {
        short8 kf = *(const short8*)&Kc[((kk * 2 + hh) * 64 + i * 32 + q31) * 8];
        sf[i] = __builtin_amdgcn_mfma_f32_32x32x16_bf16(kf, qf[kk],
                                                        kk == 0 ? zero16 : sf[i], 0, 0, 0);
      }
  };

  auto softmax_tile = [&](f32x16 (&sf)[2], int st, unsigned (&pw)[2][8], float (&rs)[4]) {
    if (mf) {
      const float* mrow = mask + (size_t)q * 2048 + st * 64;
#pragma unroll
      for (int i = 0; i < 2; ++i)
#pragma unroll
        for (int r = 0; r < 16; ++r)
          sf[i][r] += mrow[32 * i + (r & 7) + 16 * ((r >> 3) & 1) + 8 * hh] * LOG2E;
    }
#pragma unroll
    for (int i = 0; i < 2; ++i)
#pragma unroll
      for (int v = 0; v < 8; ++v) {
        float p0 = __builtin_amdgcn_exp2f(sf[i][2 * v]);
        float p1 = __builtin_amdgcn_exp2f(sf[i][2 * v + 1]);
        rs[v & 3] += p0 + p1;
        __hip_bfloat162 t2 = __float22bfloat162_rn(make_float2(p0, p1));
        pw[i][v] = *(unsigned*)&t2;
      }
  };

  auto pv_tile = [&](const unsigned short* Vc, unsigned (&pw)[2][8], f32x16 (&o)[2]) {
#pragma unroll
    for (int kk = 0; kk < 4; ++kk) {
      union { unsigned u[4]; short8 s8; } pb;
#pragma unroll
      for (int v = 0; v < 4; ++v) pb.u[v] = pw[kk >> 1][(kk & 1) * 4 + v];
#pragma unroll
      for (int d = 0; d < 2; ++d) {
        short8 vf = *(const short8*)&Vc[((kk * 2 + hh) * 64 + d * 32 + q31) * 8];
        o[d] = __builtin_amdgcn_mfma_f32_32x32x16_bf16(vf, pb.s8, o[d], 0, 0, 0);
      }
    }
  };

  stage(0, 0);
  stage(1, 1);
  for (int st = 0; st < 32; st += 2) {
    __syncthreads();
    if (st + 2 < 32) { stage(st + 2, (st + 2) & 3); stage(st + 3, (st + 3) & 3); }
    f32x16 sfA[2], sfB[2];
    unsigned pwA[2][8], pwB[2][8];
    qk_tile(&Ks[(st & 3) * 4096], sfA);
    qk_tile(&Ks[((st + 1) & 3) * 4096], sfB);
    softmax_tile(sfA, st, pwA, rsA);
    pv_tile(&Vs[(st & 3) * 4096], pwA, oA);
    softmax_tile(sfB, st + 1, pwB, rsB);
    pv_tile(&Vs[((st + 1) & 3) * 4096], pwB, oB);
  }
  float lrun = ((rsA[0] + rsA[1]) + (rsA[2] + rsA[3])) +
               ((rsB[0] + rsB[1]) + (rsB[2] + rsB[3]));
  lrun += __shfl_xor(lrun, 32);
  float inv = 1.f / lrun;
  unsigned short* orow = Obf + ((size_t)b * 2048 + q) * 1024 + head * 64;
#pragma unroll
  for (int d = 0; d < 2; ++d)
#pragma unroll
    for (int g = 0; g < 4; ++g) {
      ushort4 pk4;
      pk4.x = f2bf((oA[d][4 * g + 0] + oB[d][4 * g + 0]) * inv);
      pk4.y = f2bf((oA[d][4 * g + 1] + oB[d][4 * g + 1]) * inv);
      pk4.z = f2bf((oA[d][4 * g + 2] + oB[d][4 * g + 2]) * inv);
      pk4.w = f2bf((oA[d][4 * g + 3] + oB[d][4 * g + 3]) * inv);
      *(ushort4*)&orow[32 * d + 8 * g + 4 * hh] = pk4;
    }
}

extern "C" void kernel_launch(void* const* d_in, const int* in_sizes, int n_in,
                              void* d_out, int out_size, void* d_ws, size_t ws_size,
                              hipStream_t stream) {
  const float* qin  = (const float*)d_in[0];
  const float* kin  = (const float*)d_in[1];
  const float* vin  = (const float*)d_in[2];
  const float* mask = (const float*)d_in[3];
  const float* wq   = (const float*)d_in[4];
  const float* wk   = (const float*)d_in[5];
  const float* wv   = (const float*)d_in[6];
  const float* wo   = (const float*)d_in[7];

  float* out    = (float*)d_out;          // (B,L,1024)
  float* kcache = out + 4194304;          // (B,H,DK,S)
  float* vcache = kcache + 4194304;       // (B,H,S,DK)

  char* ws = (char*)d_ws;
  const size_t MB8 = 8388608ull;
  if (ws_size < 8 * MB8 + 4) return;
  unsigned short* wqb = (unsigned short*)(ws + 3 * MB8);
  unsigned short* wkb = (unsigned short*)(ws + 3 * MB8 + 2097152);
  unsigned short* wvb = (unsigned short*)(ws + 3 * MB8 + 2 * 2097152);
  unsigned short* wob = (unsigned short*)(ws + 3 * MB8 + 3 * 2097152);
  unsigned short* Qb  = (unsigned short*)(ws + 4 * MB8);
  unsigned short* Kb  = (unsigned short*)(ws + 5 * MB8);
  unsigned short* Vt  = (unsigned short*)(ws + 6 * MB8);
  unsigned short* Ob  = (unsigned short*)(ws + 7 * MB8);
  int* flag = (int*)(ws + 8 * MB8);

  hipMemsetAsync(flag, 0, 4, stream);
  hipLaunchKernelGGL(cvt_kernel, dim3(8192), dim3(256), 0, stream,
                     wq, wk, wv, wo, mask, wqb, wkb, wvb, wob, flag);
  hipLaunchKernelGGL(gemm_qkv_kernel, dim3(32, 8, 3), dim3(512), 0, stream,
                     qin, kin, vin, wqb, wkb, wvb, Qb, Kb, Vt, kcache, vcache);
  hipLaunchKernelGGL(attn_kernel, dim3(16, 32), dim3(256), 0, stream,
                     Qb, Kb, Vt, mask, flag, Ob);
  hipLaunchKernelGGL(gemm_o_kernel, dim3(32, 16), dim3(512), 0, stream,
                     Ob, wob, out);
}

// Round 19
// 132.493 us; speedup vs baseline: 1.1149x; 1.1149x over previous
//
#include <hip/hip_runtime.h>
#include <hip/hip_bf16.h>

typedef __attribute__((ext_vector_type(4))) float f32x4;
typedef __attribute__((ext_vector_type(16))) float f32x16;
typedef __attribute__((ext_vector_type(8))) short short8;

#define LOG2E 1.4426950408889634f

__device__ __forceinline__ unsigned short f2bf(float f) {
  union { float f; unsigned u; } v; v.f = f;
  unsigned r = v.u + 0x7FFFu + ((v.u >> 16) & 1u);
  return (unsigned short)(r >> 16);
}

__device__ __forceinline__ void gload_lds16(const unsigned short* g, unsigned short* l) {
  __builtin_amdgcn_global_load_lds((const __attribute__((address_space(1))) void*)g,
                                   (__attribute__((address_space(3))) void*)l, 16, 0, 0);
}

// -------- weights f32 -> bf16 + mask nonzero flag (activations fused in GEMM) --------
__global__ void cvt_kernel(const float* __restrict__ wq, const float* __restrict__ wk,
                           const float* __restrict__ wv, const float* __restrict__ wo,
                           const float* __restrict__ mask,
                           unsigned short* __restrict__ wqb, unsigned short* __restrict__ wkb,
                           unsigned short* __restrict__ wvb, unsigned short* __restrict__ wob,
                           int* __restrict__ flag) {
  const size_t W1 = 262144;  // 1M f32 / 4 per unit
  size_t u = (size_t)blockIdx.x * 256 + threadIdx.x;
  const float* src; unsigned short* dst; size_t loc;
  if (u < W1)          { src = wq; dst = wqb; loc = u; }
  else if (u < 2 * W1) { src = wk; dst = wkb; loc = u - W1; }
  else if (u < 3 * W1) { src = wv; dst = wvb; loc = u - 2 * W1; }
  else if (u < 4 * W1) { src = wo; dst = wob; loc = u - 3 * W1; }
  else {
    loc = u - 4 * W1;  // mask: 4M f32 = 1M units
    float4 f = ((const float4*)mask)[loc];
    if (f.x != 0.f || f.y != 0.f || f.z != 0.f || f.w != 0.f) atomicOr(flag, 1);
    return;
  }
  float4 f = ((const float4*)src)[loc];
  ushort4 o;
  o.x = f2bf(f.x); o.y = f2bf(f.y); o.z = f2bf(f.z); o.w = f2bf(f.w);
  ((ushort4*)dst)[loc] = o;
}

// ---------------- QKV projections: C = A_f32 * B_bf16^T, fused conversion ----
// BM=BN=128, BK=32, 512 threads (8 waves, 4m x 2n). A staged via registers
// (f32 load -> f2bf -> ds_write_b128 at the pre-swizzled slot) with the T14
// issue-early/write-late split so HBM latency hides under the MFMA block.
// B staged via global_load_lds (bf16 weights). XOR-swizzled LDS, dbuf,
// 1 barrier per K-step. NO XCD swizzle: default dispatch (orig = bx + 32*by,
// bx fastest) puts all 8 n-blocks of a given m-panel on the SAME XCD
// (orig mod 8 = bx mod 8), so the f32 A panel is L2-reused for free --
// r18's swizzle broke exactly this (FETCH 49 -> 199 MB).
__global__ __launch_bounds__(512)
void gemm_qkv_kernel(const float* __restrict__ qin, const float* __restrict__ kin,
                     const float* __restrict__ vin,
                     const unsigned short* __restrict__ wq, const unsigned short* __restrict__ wk,
                     const unsigned short* __restrict__ wv,
                     unsigned short* __restrict__ Qbf, unsigned short* __restrict__ Kbf,
                     unsigned short* __restrict__ Vt,
                     float* __restrict__ kcache, float* __restrict__ vcache) {
  __shared__ __align__(16) unsigned short As[2 * 4096];
  __shared__ __align__(16) unsigned short Bs[2 * 4096];
  const int z = blockIdx.z;
  const float* Af = (z == 0) ? qin : (z == 1) ? kin : vin;
  const unsigned short* B = (z == 0) ? wq : (z == 1) ? wk : wv;
  const int m0 = blockIdx.x * 128, n0 = blockIdx.y * 128;
  const int t = threadIdx.x, lane = t & 63, w = t >> 6;
  const int wr = (w >> 1) << 5, wc = (w & 1) << 6;
  const int lo = lane & 15, hi = lane >> 4;
  const int swz = (hi ^ ((lo >> 1) & 3)) * 8;

  f32x4 acc[2][4];
#pragma unroll
  for (int i = 0; i < 2; ++i)
#pragma unroll
    for (int j = 0; j < 4; ++j) acc[i][j] = f32x4{0.f, 0.f, 0.f, 0.f};

  const int c0 = t, row0 = c0 >> 2;
  const int gsw0 = ((c0 & 3) ^ ((row0 >> 1) & 3)) << 3;
  const float* Arow = Af + (size_t)(m0 + row0) * 1024 + gsw0;
  const unsigned short* Br0 = B + (size_t)(n0 + row0) * 1024 + gsw0;

  float4 a0, a1;
  auto loadA = [&](int kt) {
    a0 = *(const float4*)(Arow + kt);
    a1 = *(const float4*)(Arow + kt + 4);
  };
  auto writeA = [&](int buf) {
    short8 w8;
    w8[0] = (short)f2bf(a0.x); w8[1] = (short)f2bf(a0.y);
    w8[2] = (short)f2bf(a0.z); w8[3] = (short)f2bf(a0.w);
    w8[4] = (short)f2bf(a1.x); w8[5] = (short)f2bf(a1.y);
    w8[6] = (short)f2bf(a1.z); w8[7] = (short)f2bf(a1.w);
    *(short8*)&As[buf * 4096 + c0 * 8] = w8;
  };
  auto stageB = [&](int kt, int buf) { gload_lds16(Br0 + kt, &Bs[buf * 4096 + c0 * 8]); };

  loadA(0); stageB(0, 0); writeA(0);
  for (int it = 0; it < 32; ++it) {
    __syncthreads();  // buf it&1 ready (A ds_writes + B gload drained); (it+1)&1 free
    if (it + 1 < 32) { loadA((it + 1) * 32); stageB((it + 1) * 32, (it + 1) & 1); }
    const unsigned short* Ac = &As[(it & 1) * 4096];
    const unsigned short* Bc = &Bs[(it & 1) * 4096];
    short8 af[2], bfr[4];
#pragma unroll
    for (int i = 0; i < 2; ++i) af[i]  = *(const short8*)&Ac[(wr + i*16 + lo) * 32 + swz];
#pragma unroll
    for (int j = 0; j < 4; ++j) bfr[j] = *(const short8*)&Bc[(wc + j*16 + lo) * 32 + swz];
#pragma unroll
    for (int i = 0; i < 2; ++i)
#pragma unroll
      for (int j = 0; j < 4; ++j)
        acc[i][j] = __builtin_amdgcn_mfma_f32_16x16x32_bf16(af[i], bfr[j], acc[i][j], 0, 0, 0);
    if (it + 1 < 32) writeA((it + 1) & 1);  // late write: loads landed under the MFMAs
  }

#pragma unroll
  for (int i = 0; i < 2; ++i)
#pragma unroll
    for (int j = 0; j < 4; ++j) {
      int n = n0 + wc + j * 16 + lo;
      int head = n >> 6, dk = n & 63;
      int mbase = m0 + wr + i * 16 + hi * 4;
      int b = mbase >> 11, sbase = mbase & 2047;
      size_t bh = (size_t)b * 16 + head;
      if (z == 0) {
#pragma unroll
        for (int r = 0; r < 4; ++r)
          Qbf[(bh * 2048 + sbase + r) * 64 + dk] = f2bf(acc[i][j][r] * LOG2E);
      } else if (z == 1) {
#pragma unroll
        for (int r = 0; r < 4; ++r)
          Kbf[(bh * 2048 + sbase + r) * 64 + dk] = f2bf(acc[i][j][r]);
        float4 kv4;
        kv4.x = acc[i][j][0]; kv4.y = acc[i][j][1];
        kv4.z = acc[i][j][2]; kv4.w = acc[i][j][3];
        *(float4*)&kcache[(bh * 64 + dk) * 2048 + sbase] = kv4;
      } else {
#pragma unroll
        for (int r = 0; r < 4; ++r)
          vcache[(bh * 2048 + sbase + r) * 64 + dk] = acc[i][j][r];
        ushort4 vt4;
        vt4.x = f2bf(acc[i][j][0]); vt4.y = f2bf(acc[i][j][1]);
        vt4.z = f2bf(acc[i][j][2]); vt4.w = f2bf(acc[i][j][3]);
        *(ushort4*)&Vt[(bh * 64 + dk) * 2048 + sbase] = vt4;
      }
    }
}

// ---------------- output projection (bf16 x bf16 -> f32) ----------------
__global__ __launch_bounds__(512)
void gemm_o_kernel(const unsigned short* __restrict__ A, const unsigned short* __restrict__ B,
                   float* __restrict__ C) {
  __shared__ __align__(16) unsigned short As[2 * 4096];
  __shared__ __align__(16) unsigned short Bs[2 * 4096];
  const int m0 = blockIdx.x * 128, n0 = blockIdx.y * 128;
  const int t = threadIdx.x, lane = t & 63, w = t >> 6;
  const int wr = (w >> 1) << 5, wc = (w & 1) << 6;
  const int lo = lane & 15, hi = lane >> 4;
  const int swz = (hi ^ ((lo >> 1) & 3)) * 8;
  f32x4 acc[2][4];
#pragma unroll
  for (int i = 0; i < 2; ++i)
#pragma unroll
    for (int j = 0; j < 4; ++j) acc[i][j] = f32x4{0.f, 0.f, 0.f, 0.f};

  const int c0 = t, row0 = c0 >> 2;
  const int gsw0 = ((c0 & 3) ^ ((row0 >> 1) & 3)) << 3;
  const unsigned short* Ar0 = A + (size_t)(m0 + row0) * 1024 + gsw0;
  const unsigned short* Br0 = B + (size_t)(n0 + row0) * 1024 + gsw0;

  auto stage = [&](int kt, int buf) {
    gload_lds16(Ar0 + kt, &As[buf * 4096 + c0 * 8]);
    gload_lds16(Br0 + kt, &Bs[buf * 4096 + c0 * 8]);
  };

  stage(0, 0);
  for (int it = 0; it < 32; ++it) {
    __syncthreads();
    if (it + 1 < 32) stage((it + 1) * 32, (it + 1) & 1);
    const unsigned short* Ac = &As[(it & 1) * 4096];
    const unsigned short* Bc = &Bs[(it & 1) * 4096];
    short8 af[2], bfr[4];
#pragma unroll
    for (int i = 0; i < 2; ++i) af[i]  = *(const short8*)&Ac[(wr + i*16 + lo) * 32 + swz];
#pragma unroll
    for (int j = 0; j < 4; ++j) bfr[j] = *(const short8*)&Bc[(wc + j*16 + lo) * 32 + swz];
#pragma unroll
    for (int i = 0; i < 2; ++i)
#pragma unroll
      for (int j = 0; j < 4; ++j)
        acc[i][j] = __builtin_amdgcn_mfma_f32_16x16x32_bf16(af[i], bfr[j], acc[i][j], 0, 0, 0);
  }
#pragma unroll
  for (int i = 0; i < 2; ++i)
#pragma unroll
    for (int j = 0; j < 4; ++j)
#pragma unroll
      for (int r = 0; r < 4; ++r)
        C[(size_t)(m0 + wr + i * 16 + hi * 4 + r) * 1024 + n0 + wc + j * 16 + lo] = acc[i][j][r];
}

// ---------------- flash attention, swapped-operand 32x32 MFMA (round-8) -----
// Single-pass. 4 KV buffer pairs (64KB LDS), ONE barrier per TWO tiles;
// compute order QK(t) -> QK(t+1) -> exp(t) -> PV(t) -> exp(t+1) -> PV(t+1).
// Scale-invariant softmax in log2 domain (Q pre-scaled by log2e): P = exp2(s),
// no max subtraction. Row-sum l via ones-A MFMA.
__global__ __launch_bounds__(256, 2)
void attn_kernel(const unsigned short* __restrict__ Qbf,
                 const unsigned short* __restrict__ Kbf,
                 const unsigned short* __restrict__ Vtb,
                 const float* __restrict__ mask, const int* __restrict__ flag,
                 unsigned short* __restrict__ Obf) {
  __shared__ __align__(16) unsigned short Ks[4 * 4096];  // [buf][d8][slot64][8]
  __shared__ __align__(16) unsigned short Vs[4 * 4096];  // [buf][s8][dk64][8]
  const int t = threadIdx.x, lane = t & 63, w = t >> 6;
  const int q31 = lane & 31, hh = lane >> 5;

  int orig = blockIdx.x + 16 * blockIdx.y;
  int logical = (orig & 7) * 64 + (orig >> 3);
  const int bh = logical >> 4;
  const int b = bh >> 4, head = bh & 15;
  const int q = (logical & 15) * 128 + w * 32 + q31;
  const int mf = *flag;

  short8 qf[4];
  const unsigned short* Qrow = Qbf + ((size_t)bh * 2048 + q) * 64 + hh * 8;
#pragma unroll
  for (int kk = 0; kk < 4; ++kk) qf[kk] = *(const short8*)(Qrow + kk * 16);

  f32x16 o[2], osum, zero16;
#pragma unroll
  for (int d = 0; d < 2; ++d)
#pragma unroll
    for (int r = 0; r < 16; ++r) o[d][r] = 0.f;
#pragma unroll
  for (int r = 0; r < 16; ++r) { osum[r] = 0.f; zero16[r] = 0.f; }
  short8 ones8;
#pragma unroll
  for (int e = 0; e < 8; ++e) ones8[e] = (short)0x3F80;  // bf16 1.0

  const unsigned short* Kbase = Kbf + (size_t)bh * 2048 * 64;
  const unsigned short* Vbase = Vtb + (size_t)bh * 64 * 2048;

  auto stage = [&](int st, int buf) {
#pragma unroll
    for (int cc = 0; cc < 2; ++cc) {
      int c = t + cc * 256;
      int hi6 = c >> 6, lo6 = c & 63;
      int pr = (lo6 & ~12) | ((lo6 & 4) << 1) | ((lo6 >> 1) & 4);  // bit2<->bit3
      gload_lds16(Kbase + (size_t)(st * 64 + pr) * 64 + hi6 * 8, &Ks[buf * 4096 + c * 8]);
      gload_lds16(Vbase + (size_t)lo6 * 2048 + st * 64 + hi6 * 8, &Vs[buf * 4096 + c * 8]);
    }
  };

  auto qk_tile = [&](const unsigned short* Kc, f32x16 (&sf)[2]) {
#pragma unroll
    for (int kk = 0; kk < 4; ++kk)
#pragma unroll
      for (int i = 0; i < 2; ++i) {
        short8 kf = *(const short8*)&Kc[((kk * 2 + hh) * 64 + i * 32 + q31) * 8];
        sf[i] = __builtin_amdgcn_mfma_f32_32x32x16_bf16(kf, qf[kk],
                                                        kk == 0 ? zero16 : sf[i], 0, 0, 0);
      }
  };

  auto softmax_tile = [&](f32x16 (&sf)[2], int st, unsigned (&pw)[2][8]) {
    if (mf) {
      const float* mrow = mask + (size_t)q * 2048 + st * 64;
#pragma unroll
      for (int i = 0; i < 2; ++i)
#pragma unroll
        for (int r = 0; r < 16; ++r)
          sf[i][r] += mrow[32 * i + (r & 7) + 16 * ((r >> 3) & 1) + 8 * hh] * LOG2E;
    }
#pragma unroll
    for (int i = 0; i < 2; ++i)
#pragma unroll
      for (int v = 0; v < 8; ++v) {
        float p0 = __builtin_amdgcn_exp2f(sf[i][2 * v]);
        float p1 = __builtin_amdgcn_exp2f(sf[i][2 * v + 1]);
        __hip_bfloat162 t2 = __float22bfloat162_rn(make_float2(p0, p1));
        pw[i][v] = *(unsigned*)&t2;
      }
  };

  auto pv_tile = [&](const unsigned short* Vc, unsigned (&pw)[2][8]) {
#pragma unroll
    for (int kk = 0; kk < 4; ++kk) {
      union { unsigned u[4]; short8 s8; } pb;
#pragma unroll
      for (int v = 0; v < 4; ++v) pb.u[v] = pw[kk >> 1][(kk & 1) * 4 + v];
#pragma unroll
      for (int d = 0; d < 2; ++d) {
        short8 vf = *(const short8*)&Vc[((kk * 2 + hh) * 64 + d * 32 + q31) * 8];
        o[d] = __builtin_amdgcn_mfma_f32_32x32x16_bf16(vf, pb.s8, o[d], 0, 0, 0);
      }
      osum = __builtin_amdgcn_mfma_f32_32x32x16_bf16(ones8, pb.s8, osum, 0, 0, 0);
    }
  };

  stage(0, 0);
  stage(1, 1);
  for (int st = 0; st < 32; st += 2) {
    __syncthreads();
    if (st + 2 < 32) { stage(st + 2, (st + 2) & 3); stage(st + 3, (st + 3) & 3); }
    f32x16 sfA[2], sfB[2];
    unsigned pwA[2][8], pwB[2][8];
    qk_tile(&Ks[(st & 3) * 4096], sfA);
    qk_tile(&Ks[((st + 1) & 3) * 4096], sfB);
    softmax_tile(sfA, st, pwA);
    pv_tile(&Vs[(st & 3) * 4096], pwA);
    softmax_tile(sfB, st + 1, pwB);
    pv_tile(&Vs[((st + 1) & 3) * 4096], pwB);
  }
  float inv = 1.f / osum[0];
  unsigned short* orow = Obf + ((size_t)b * 2048 + q) * 1024 + head * 64;
#pragma unroll
  for (int d = 0; d < 2; ++d)
#pragma unroll
    for (int g = 0; g < 4; ++g) {
      ushort4 pk4;
      pk4.x = f2bf(o[d][4 * g + 0] * inv);
      pk4.y = f2bf(o[d][4 * g + 1] * inv);
      pk4.z = f2bf(o[d][4 * g + 2] * inv);
      pk4.w = f2bf(o[d][4 * g + 3] * inv);
      *(ushort4*)&orow[32 * d + 8 * g + 4 * hh] = pk4;
    }
}

extern "C" void kernel_launch(void* const* d_in, const int* in_sizes, int n_in,
                              void* d_out, int out_size, void* d_ws, size_t ws_size,
                              hipStream_t stream) {
  const float* qin  = (const float*)d_in[0];
  const float* kin  = (const float*)d_in[1];
  const float* vin  = (const float*)d_in[2];
  const float* mask = (const float*)d_in[3];
  const float* wq   = (const float*)d_in[4];
  const float* wk   = (const float*)d_in[5];
  const float* wv   = (const float*)d_in[6];
  const float* wo   = (const float*)d_in[7];

  float* out    = (float*)d_out;          // (B,L,1024)
  float* kcache = out + 4194304;          // (B,H,DK,S)
  float* vcache = kcache + 4194304;       // (B,H,S,DK)

  char* ws = (char*)d_ws;
  const size_t MB8 = 8388608ull;
  if (ws_size < 8 * MB8 + 4) return;
  unsigned short* wqb = (unsigned short*)(ws + 3 * MB8);
  unsigned short* wkb = (unsigned short*)(ws + 3 * MB8 + 2097152);
  unsigned short* wvb = (unsigned short*)(ws + 3 * MB8 + 2 * 2097152);
  unsigned short* wob = (unsigned short*)(ws + 3 * MB8 + 3 * 2097152);
  unsigned short* Qb  = (unsigned short*)(ws + 4 * MB8);
  unsigned short* Kb  = (unsigned short*)(ws + 5 * MB8);
  unsigned short* Vt  = (unsigned short*)(ws + 6 * MB8);
  unsigned short* Ob  = (unsigned short*)(ws + 7 * MB8);
  int* flag = (int*)(ws + 8 * MB8);

  hipMemsetAsync(flag, 0, 4, stream);
  hipLaunchKernelGGL(cvt_kernel, dim3(8192), dim3(256), 0, stream,
                     wq, wk, wv, wo, mask, wqb, wkb, wvb, wob, flag);
  hipLaunchKernelGGL(gemm_qkv_kernel, dim3(32, 8, 3), dim3(512), 0, stream,
                     qin, kin, vin, wqb, wkb, wvb, Qb, Kb, Vt, kcache, vcache);
  hipLaunchKernelGGL(attn_kernel, dim3(16, 32), dim3(256), 0, stream,
                     Qb, Kb, Vt, mask, flag, Ob);
  hipLaunchKernelGGL(gemm_o_kernel, dim3(32, 8), dim3(512), 0, stream,
                     Ob, wob, out);
}

// Round 20
// 125.603 us; speedup vs baseline: 1.1761x; 1.0549x over previous
//
#include <hip/hip_runtime.h>
#include <hip/hip_bf16.h>

typedef __attribute__((ext_vector_type(4))) float f32x4;
typedef __attribute__((ext_vector_type(8))) short short8;

#define LOG2E 1.4426950408889634f

__device__ __forceinline__ unsigned short f2bf(float f) {
  union { float f; unsigned u; } v; v.f = f;
  unsigned r = v.u + 0x7FFFu + ((v.u >> 16) & 1u);
  return (unsigned short)(r >> 16);
}

__device__ __forceinline__ void gload_lds16(const unsigned short* g, unsigned short* l) {
  __builtin_amdgcn_global_load_lds((const __attribute__((address_space(1))) void*)g,
                                   (__attribute__((address_space(3))) void*)l, 16, 0, 0);
}

// -------- weights f32 -> bf16 + mask nonzero flag (activations fused in GEMM) --------
__global__ void cvt_kernel(const float* __restrict__ wq, const float* __restrict__ wk,
                           const float* __restrict__ wv, const float* __restrict__ wo,
                           const float* __restrict__ mask,
                           unsigned short* __restrict__ wqb, unsigned short* __restrict__ wkb,
                           unsigned short* __restrict__ wvb, unsigned short* __restrict__ wob,
                           int* __restrict__ flag) {
  const size_t W1 = 262144;
  size_t u = (size_t)blockIdx.x * 256 + threadIdx.x;
  const float* src; unsigned short* dst; size_t loc;
  if (u < W1)          { src = wq; dst = wqb; loc = u; }
  else if (u < 2 * W1) { src = wk; dst = wkb; loc = u - W1; }
  else if (u < 3 * W1) { src = wv; dst = wvb; loc = u - 2 * W1; }
  else if (u < 4 * W1) { src = wo; dst = wob; loc = u - 3 * W1; }
  else {
    loc = u - 4 * W1;
    float4 f = ((const float4*)mask)[loc];
    if (f.x != 0.f || f.y != 0.f || f.z != 0.f || f.w != 0.f) atomicOr(flag, 1);
    return;
  }
  float4 f = ((const float4*)src)[loc];
  ushort4 o;
  o.x = f2bf(f.x); o.y = f2bf(f.y); o.z = f2bf(f.z); o.w = f2bf(f.w);
  ((ushort4*)dst)[loc] = o;
}

// ---------------- QKV projections: C = A_f32 * B_bf16^T, fused conversion ----
// r11/r19 structure (session best). NO XCD swizzle (default dispatch gives
// A-panel L2 reuse; r18's swizzle broke it: FETCH 49 -> 199 MB).
__global__ __launch_bounds__(512)
void gemm_qkv_kernel(const float* __restrict__ qin, const float* __restrict__ kin,
                     const float* __restrict__ vin,
                     const unsigned short* __restrict__ wq, const unsigned short* __restrict__ wk,
                     const unsigned short* __restrict__ wv,
                     unsigned short* __restrict__ Qbf, unsigned short* __restrict__ Kbf,
                     unsigned short* __restrict__ Vt,
                     float* __restrict__ kcache, float* __restrict__ vcache) {
  __shared__ __align__(16) unsigned short As[2 * 4096];
  __shared__ __align__(16) unsigned short Bs[2 * 4096];
  const int z = blockIdx.z;
  const float* Af = (z == 0) ? qin : (z == 1) ? kin : vin;
  const unsigned short* B = (z == 0) ? wq : (z == 1) ? wk : wv;
  const int m0 = blockIdx.x * 128, n0 = blockIdx.y * 128;
  const int t = threadIdx.x, lane = t & 63, w = t >> 6;
  const int wr = (w >> 1) << 5, wc = (w & 1) << 6;
  const int lo = lane & 15, hi = lane >> 4;
  const int swz = (hi ^ ((lo >> 1) & 3)) * 8;

  f32x4 acc[2][4];
#pragma unroll
  for (int i = 0; i < 2; ++i)
#pragma unroll
    for (int j = 0; j < 4; ++j) acc[i][j] = f32x4{0.f, 0.f, 0.f, 0.f};

  const int c0 = t, row0 = c0 >> 2;
  const int gsw0 = ((c0 & 3) ^ ((row0 >> 1) & 3)) << 3;
  const float* Arow = Af + (size_t)(m0 + row0) * 1024 + gsw0;
  const unsigned short* Br0 = B + (size_t)(n0 + row0) * 1024 + gsw0;

  float4 a0, a1;
  auto loadA = [&](int kt) {
    a0 = *(const float4*)(Arow + kt);
    a1 = *(const float4*)(Arow + kt + 4);
  };
  auto writeA = [&](int buf) {
    short8 w8;
    w8[0] = (short)f2bf(a0.x); w8[1] = (short)f2bf(a0.y);
    w8[2] = (short)f2bf(a0.z); w8[3] = (short)f2bf(a0.w);
    w8[4] = (short)f2bf(a1.x); w8[5] = (short)f2bf(a1.y);
    w8[6] = (short)f2bf(a1.z); w8[7] = (short)f2bf(a1.w);
    *(short8*)&As[buf * 4096 + c0 * 8] = w8;
  };
  auto stageB = [&](int kt, int buf) { gload_lds16(Br0 + kt, &Bs[buf * 4096 + c0 * 8]); };

  loadA(0); stageB(0, 0); writeA(0);
  for (int it = 0; it < 32; ++it) {
    __syncthreads();
    if (it + 1 < 32) { loadA((it + 1) * 32); stageB((it + 1) * 32, (it + 1) & 1); }
    const unsigned short* Ac = &As[(it & 1) * 4096];
    const unsigned short* Bc = &Bs[(it & 1) * 4096];
    short8 af[2], bfr[4];
#pragma unroll
    for (int i = 0; i < 2; ++i) af[i]  = *(const short8*)&Ac[(wr + i*16 + lo) * 32 + swz];
#pragma unroll
    for (int j = 0; j < 4; ++j) bfr[j] = *(const short8*)&Bc[(wc + j*16 + lo) * 32 + swz];
#pragma unroll
    for (int i = 0; i < 2; ++i)
#pragma unroll
      for (int j = 0; j < 4; ++j)
        acc[i][j] = __builtin_amdgcn_mfma_f32_16x16x32_bf16(af[i], bfr[j], acc[i][j], 0, 0, 0);
    if (it + 1 < 32) writeA((it + 1) & 1);
  }

#pragma unroll
  for (int i = 0; i < 2; ++i)
#pragma unroll
    for (int j = 0; j < 4; ++j) {
      int n = n0 + wc + j * 16 + lo;
      int head = n >> 6, dk = n & 63;
      int mbase = m0 + wr + i * 16 + hi * 4;
      int b = mbase >> 11, sbase = mbase & 2047;
      size_t bh = (size_t)b * 16 + head;
      if (z == 0) {
#pragma unroll
        for (int r = 0; r < 4; ++r)
          Qbf[(bh * 2048 + sbase + r) * 64 + dk] = f2bf(acc[i][j][r] * LOG2E);
      } else if (z == 1) {
#pragma unroll
        for (int r = 0; r < 4; ++r)
          Kbf[(bh * 2048 + sbase + r) * 64 + dk] = f2bf(acc[i][j][r]);
        float4 kv4;
        kv4.x = acc[i][j][0]; kv4.y = acc[i][j][1];
        kv4.z = acc[i][j][2]; kv4.w = acc[i][j][3];
        *(float4*)&kcache[(bh * 64 + dk) * 2048 + sbase] = kv4;
      } else {
#pragma unroll
        for (int r = 0; r < 4; ++r)
          vcache[(bh * 2048 + sbase + r) * 64 + dk] = acc[i][j][r];
        ushort4 vt4;
        vt4.x = f2bf(acc[i][j][0]); vt4.y = f2bf(acc[i][j][1]);
        vt4.z = f2bf(acc[i][j][2]); vt4.w = f2bf(acc[i][j][3]);
        *(ushort4*)&Vt[(bh * 64 + dk) * 2048 + sbase] = vt4;
      }
    }
}

// ---------------- output projection (bf16 x bf16 -> f32) ----------------
__global__ __launch_bounds__(512)
void gemm_o_kernel(const unsigned short* __restrict__ A, const unsigned short* __restrict__ B,
                   float* __restrict__ C) {
  __shared__ __align__(16) unsigned short As[2 * 4096];
  __shared__ __align__(16) unsigned short Bs[2 * 4096];
  const int m0 = blockIdx.x * 128, n0 = blockIdx.y * 128;
  const int t = threadIdx.x, lane = t & 63, w = t >> 6;
  const int wr = (w >> 1) << 5, wc = (w & 1) << 6;
  const int lo = lane & 15, hi = lane >> 4;
  const int swz = (hi ^ ((lo >> 1) & 3)) * 8;
  f32x4 acc[2][4];
#pragma unroll
  for (int i = 0; i < 2; ++i)
#pragma unroll
    for (int j = 0; j < 4; ++j) acc[i][j] = f32x4{0.f, 0.f, 0.f, 0.f};

  const int c0 = t, row0 = c0 >> 2;
  const int gsw0 = ((c0 & 3) ^ ((row0 >> 1) & 3)) << 3;
  const unsigned short* Ar0 = A + (size_t)(m0 + row0) * 1024 + gsw0;
  const unsigned short* Br0 = B + (size_t)(n0 + row0) * 1024 + gsw0;

  auto stage = [&](int kt, int buf) {
    gload_lds16(Ar0 + kt, &As[buf * 4096 + c0 * 8]);
    gload_lds16(Br0 + kt, &Bs[buf * 4096 + c0 * 8]);
  };

  stage(0, 0);
  for (int it = 0; it < 32; ++it) {
    __syncthreads();
    if (it + 1 < 32) stage((it + 1) * 32, (it + 1) & 1);
    const unsigned short* Ac = &As[(it & 1) * 4096];
    const unsigned short* Bc = &Bs[(it & 1) * 4096];
    short8 af[2], bfr[4];
#pragma unroll
    for (int i = 0; i < 2; ++i) af[i]  = *(const short8*)&Ac[(wr + i*16 + lo) * 32 + swz];
#pragma unroll
    for (int j = 0; j < 4; ++j) bfr[j] = *(const short8*)&Bc[(wc + j*16 + lo) * 32 + swz];
#pragma unroll
    for (int i = 0; i < 2; ++i)
#pragma unroll
      for (int j = 0; j < 4; ++j)
        acc[i][j] = __builtin_amdgcn_mfma_f32_16x16x32_bf16(af[i], bfr[j], acc[i][j], 0, 0, 0);
  }
#pragma unroll
  for (int i = 0; i < 2; ++i)
#pragma unroll
    for (int j = 0; j < 4; ++j)
#pragma unroll
      for (int r = 0; r < 4; ++r)
        C[(size_t)(m0 + wr + i * 16 + hi * 4 + r) * 1024 + n0 + wc + j * 16 + lo] = acc[i][j][r];
}

// ---------------- flash attention, 16x16x32 MFMA, 16 q-rows/wave -------------
// 512 threads = 8 waves x 16 q = 128 q/block; grid (16,32) = 512 blocks ->
// 4096 waves = 4 waves/SIMD (2x round 8's 32x32 version; same KV locality,
// same LDS). Swapped S^T = mfma(K, Q): lane owns q = lane&15.
// K rows staged with bit-rotation pi(i) = (i&35)|((i&12)<<1)|((i&16)>>2)
// so lane reg (f2,r) = S_true[32*(f2>>1) + 8*(lane>>4) + 4*(f2&1) + r]
// == exactly B-frag element e = 4*(f2&1)+r of PV k-step (f2>>1): the P->B
// repack is pure in-lane cvt_pk. K/V reads are row-stride-128B -> XOR group
// swizzle g^(row&7) (source-side pre-swizzle + read XOR) -> 2-way, free.
// Row-sum via ones-A MFMA (fully reduced). 2-tile window, 4 buffer pairs.
__global__ __launch_bounds__(512, 4)
void attn_kernel(const unsigned short* __restrict__ Qbf,
                 const unsigned short* __restrict__ Kbf,
                 const unsigned short* __restrict__ Vtb,
                 const float* __restrict__ mask, const int* __restrict__ flag,
                 unsigned short* __restrict__ Obf) {
  __shared__ __align__(16) unsigned short Ks[4 * 4096];  // [buf][row64][grp8][8]
  __shared__ __align__(16) unsigned short Vs[4 * 4096];  // [buf][dk64][grp8][8]
  const int t = threadIdx.x, lane = t & 63, w = t >> 6;
  const int lo = lane & 15, hh = lane >> 4;  // q-col, 4-row group

  // XCD-aware swizzle: 512 blocks, 8 XCDs, 64 blocks/XCD -> 4 bh per XCD
  int orig = blockIdx.x + 16 * blockIdx.y;
  int logical = (orig & 7) * 64 + (orig >> 3);
  const int bh = logical >> 4;
  const int b = bh >> 4, head = bh & 15;
  const int q = (logical & 15) * 128 + w * 16 + lo;
  const int mf = *flag;

  short8 qf[2];
  const unsigned short* Qrow = Qbf + ((size_t)bh * 2048 + q) * 64 + hh * 8;
#pragma unroll
  for (int kk = 0; kk < 2; ++kk) qf[kk] = *(const short8*)(Qrow + kk * 32);

  f32x4 o[4], osum, zero4;
#pragma unroll
  for (int d = 0; d < 4; ++d)
#pragma unroll
    for (int r = 0; r < 4; ++r) o[d][r] = 0.f;
#pragma unroll
  for (int r = 0; r < 4; ++r) { osum[r] = 0.f; zero4[r] = 0.f; }
  short8 ones8;
#pragma unroll
  for (int e = 0; e < 8; ++e) ones8[e] = (short)0x3F80;  // bf16 1.0

  const unsigned short* Kbase = Kbf + (size_t)bh * 2048 * 64;
  const unsigned short* Vbase = Vtb + (size_t)bh * 64 * 2048;

  auto stage = [&](int st, int buf) {
    int c = t;  // 512 slots per tensor, lane-contiguous 16B (HW contract)
    int j = c >> 3, g = c & 7;
    // K: staged row j holds true row pi(j); group pre-swizzled by j&7
    int pj = (j & 35) | ((j & 12) << 1) | ((j & 16) >> 2);
    gload_lds16(Kbase + (size_t)(st * 64 + pj) * 64 + ((g ^ (j & 7)) << 3),
                &Ks[buf * 4096 + c * 8]);
    // V^T: [dk][s] rows; group pre-swizzled by dk&7
    gload_lds16(Vbase + (size_t)j * 2048 + st * 64 + ((g ^ (j & 7)) << 3),
                &Vs[buf * 4096 + c * 8]);
  };

  auto qk_tile = [&](const unsigned short* Kc, f32x4 (&sf)[4]) {
#pragma unroll
    for (int kk = 0; kk < 2; ++kk)
#pragma unroll
      for (int f2 = 0; f2 < 4; ++f2) {
        int j = f2 * 16 + lo;
        int g = (kk * 4 + hh) ^ (lo & 7);
        short8 kf = *(const short8*)&Kc[j * 64 + g * 8];
        sf[f2] = __builtin_amdgcn_mfma_f32_16x16x32_bf16(kf, qf[kk],
                                                         kk == 0 ? zero4 : sf[f2], 0, 0, 0);
      }
  };

  auto softmax_tile = [&](f32x4 (&sf)[4], int st, unsigned (&pw)[2][4]) {
    if (mf) {
      const float* mrow = mask + (size_t)q * 2048 + st * 64;
#pragma unroll
      for (int f2 = 0; f2 < 4; ++f2)
#pragma unroll
        for (int r = 0; r < 4; ++r)
          sf[f2][r] += mrow[32 * (f2 >> 1) + 8 * hh + 4 * (f2 & 1) + r] * LOG2E;
    }
#pragma unroll
    for (int f2 = 0; f2 < 4; ++f2)
#pragma unroll
      for (int r = 0; r < 4; ++r) sf[f2][r] = __builtin_amdgcn_exp2f(sf[f2][r]);
    // B-frag word v of k-step ks: pack(P(f2=2ks+(v>>1), r=2(v&1)), r+1)
#pragma unroll
    for (int ks = 0; ks < 2; ++ks)
#pragma unroll
      for (int v = 0; v < 4; ++v) {
        __hip_bfloat162 t2 = __float22bfloat162_rn(
            make_float2(sf[2 * ks + (v >> 1)][2 * (v & 1)],
                        sf[2 * ks + (v >> 1)][2 * (v & 1) + 1]));
        pw[ks][v] = *(unsigned*)&t2;
      }
  };

  auto pv_tile = [&](const unsigned short* Vc, unsigned (&pw)[2][4]) {
#pragma unroll
    for (int ks = 0; ks < 2; ++ks) {
      union { unsigned u[4]; short8 s8; } pb;
#pragma unroll
      for (int v = 0; v < 4; ++v) pb.u[v] = pw[ks][v];
#pragma unroll
      for (int d = 0; d < 4; ++d) {
        int dkr = d * 16 + lo;
        int g = (ks * 4 + hh) ^ (lo & 7);
        short8 vf = *(const short8*)&Vc[dkr * 64 + g * 8];
        o[d] = __builtin_amdgcn_mfma_f32_16x16x32_bf16(vf, pb.s8, o[d], 0, 0, 0);
      }
      osum = __builtin_amdgcn_mfma_f32_16x16x32_bf16(ones8, pb.s8, osum, 0, 0, 0);
    }
  };

  stage(0, 0);
  stage(1, 1);
  for (int st = 0; st < 32; st += 2) {
    __syncthreads();  // drains vmcnt(0): bufs st&3,(st+1)&3 ready; next two free
    if (st + 2 < 32) { stage(st + 2, (st + 2) & 3); stage(st + 3, (st + 3) & 3); }
    f32x4 sfA[4], sfB[4];
    unsigned pwA[2][4], pwB[2][4];
    qk_tile(&Ks[(st & 3) * 4096], sfA);
    qk_tile(&Ks[((st + 1) & 3) * 4096], sfB);
    softmax_tile(sfA, st, pwA);
    pv_tile(&Vs[(st & 3) * 4096], pwA);
    softmax_tile(sfB, st + 1, pwB);
    pv_tile(&Vs[((st + 1) & 3) * 4096], pwB);
  }
  // epilogue: osum[r] = full row sum for q (ones-A reduces all s, all lanes)
  float inv = 1.f / osum[0];
  unsigned short* orow = Obf + ((size_t)b * 2048 + q) * 1024 + head * 64;
#pragma unroll
  for (int d = 0; d < 4; ++d) {
    ushort4 pk4;
    pk4.x = f2bf(o[d][0] * inv);
    pk4.y = f2bf(o[d][1] * inv);
    pk4.z = f2bf(o[d][2] * inv);
    pk4.w = f2bf(o[d][3] * inv);
    *(ushort4*)&orow[d * 16 + hh * 4] = pk4;
  }
}

extern "C" void kernel_launch(void* const* d_in, const int* in_sizes, int n_in,
                              void* d_out, int out_size, void* d_ws, size_t ws_size,
                              hipStream_t stream) {
  const float* qin  = (const float*)d_in[0];
  const float* kin  = (const float*)d_in[1];
  const float* vin  = (const float*)d_in[2];
  const float* mask = (const float*)d_in[3];
  const float* wq   = (const float*)d_in[4];
  const float* wk   = (const float*)d_in[5];
  const float* wv   = (const float*)d_in[6];
  const float* wo   = (const float*)d_in[7];

  float* out    = (float*)d_out;          // (B,L,1024)
  float* kcache = out + 4194304;          // (B,H,DK,S)
  float* vcache = kcache + 4194304;       // (B,H,S,DK)

  char* ws = (char*)d_ws;
  const size_t MB8 = 8388608ull;
  if (ws_size < 8 * MB8 + 4) return;
  unsigned short* wqb = (unsigned short*)(ws + 3 * MB8);
  unsigned short* wkb = (unsigned short*)(ws + 3 * MB8 + 2097152);
  unsigned short* wvb = (unsigned short*)(ws + 3 * MB8 + 2 * 2097152);
  unsigned short* wob = (unsigned short*)(ws + 3 * MB8 + 3 * 2097152);
  unsigned short* Qb  = (unsigned short*)(ws + 4 * MB8);
  unsigned short* Kb  = (unsigned short*)(ws + 5 * MB8);
  unsigned short* Vt  = (unsigned short*)(ws + 6 * MB8);
  unsigned short* Ob  = (unsigned short*)(ws + 7 * MB8);
  int* flag = (int*)(ws + 8 * MB8);

  hipMemsetAsync(flag, 0, 4, stream);
  hipLaunchKernelGGL(cvt_kernel, dim3(8192), dim3(256), 0, stream,
                     wq, wk, wv, wo, mask, wqb, wkb, wvb, wob, flag);
  hipLaunchKernelGGL(gemm_qkv_kernel, dim3(32, 8, 3), dim3(512), 0, stream,
                     qin, kin, vin, wqb, wkb, wvb, Qb, Kb, Vt, kcache, vcache);
  hipLaunchKernelGGL(attn_kernel, dim3(16, 32), dim3(512), 0, stream,
                     Qb, Kb, Vt, mask, flag, Ob);
  hipLaunchKernelGGL(gemm_o_kernel, dim3(32, 8), dim3(512), 0, stream,
                     Ob, wob, out);
}